// Round 4
// baseline (910.285 us; speedup 1.0000x reference)
//
#include <hip/hip_runtime.h>
#include <hip/hip_bf16.h>
#include <math.h>

#define T_LEN   320000
#define NB      16
#define NROWS   32          // 16 batch * 2 ch
#define NFRAMES 625
#define NCOMP   67
#define NCH     150
#define HOPSZ   512

typedef __attribute__((ext_vector_type(8))) short short8v;
typedef __attribute__((ext_vector_type(4))) float f32x4;

// per-window constants: N, first bin k0, comp base, coeff base (float2 units)
__constant__ int cW_N[6]  = {2048,1024,512,256,128,64};
__constant__ int cW_K0[6] = {2,3,8,10,11,9};
__constant__ int cW_CB[7] = {0,4,17,29,40,46,67};
__constant__ int cW_CO[7] = {0,8192,21504,27648,30464,31232,32576};

// fused-coefficient table geometry (per window)
__constant__ int dNEp[6]  = {3072,2048,1536,1280,1152,1152};
__constant__ int dNEr[6]  = {3072,2048,1536,1280,1152,1088};
__constant__ int dFB[6]   = {0,12288,38912,57344,71424,78336};   // float2 units, total 102528
__constant__ int dStb[6]  = {0,512,768,896,960,992};             // 1536 - (N+1024)/2
// bf16-split B_T geometry: 48 cols x NEp per window (ushort units)
__constant__ int dBTb[7]  = {0,147456,245760,319488,380928,436224,491520};
// init_fused chunk mapping
__constant__ int dCPB[6]  = {12,8,6,5,5,5};                      // chunks per bin (256-wide)
__constant__ int dCKB[7]  = {0,48,152,224,279,309,414};

// ---------------- init: original DFT coeff tables, roex matrix, gauss weights ----------------
__global__ void init_tables(float2* __restrict__ coeff, float* __restrict__ Wmat,
                            float* __restrict__ gauss) {
  int gid = blockIdx.x * 256 + threadIdx.x;
  if (gid < 32576) {
    int w = 0;
    while (gid >= cW_CO[w + 1]) ++w;
    int local = gid - cW_CO[w];
    int N = cW_N[w];
    int jloc = local / N;
    int n = local - jloc * N;
    int k = cW_K0[w] + jloc;
    float win = 0.5f - 0.5f * cospif(2.0f * (float)n / (float)(N - 1));
    int r = (int)(((long long)k * (long long)n) % (long long)N);
    float ang = 2.0f * (float)r / (float)N;
    float scale = sqrtf(2.0f) / (0.5f * (float)(N - 1));
    float wc = win * scale;
    coeff[gid] = make_float2(wc * cospif(ang), wc * sinpif(ang));
  } else if (gid < 32576 + NCOMP * NCH) {
    int t = gid - 32576;
    int j = t / NCH, c = t - j * NCH;
    float erb = 1.75f + 0.25f * (float)c;
    float fc = (exp10f(erb * (1.0f / 21.366f)) - 1.0f) * (1.0f / 0.004368f);
    float erbw = 24.673f * (0.004368f * fc + 1.0f);
    float p = 4.0f * fc / erbw;
    int w = 0;
    while (j >= cW_CB[w + 1]) ++w;
    float freq = (float)(cW_K0[w] + (j - cW_CB[w])) * (32000.0f / (float)cW_N[w]);
    float g = fabsf(freq / fc - 1.0f);
    float pg = p * g;
    Wmat[j * NCH + c] = (1.0f + pg) * expf(-pg);
  } else if (gid == 32576 + NCOMP * NCH) {
    float tmp[17]; float s = 0.0f;
    for (int k = 0; k < 17; ++k) {
      float g = ((float)k - 8.0f) * 0.25f;
      tmp[k] = expf(-g * g / (2.0f * 0.08f * 0.08f));
      s += tmp[k];
    }
    for (int k = 0; k < 17; ++k) gauss[k] = tmp[k] / s;
  }
}

// ---------------- init_fused: C_j[v] = sum_n c_n * h[n + 1024 - v] ----------------
__global__ __launch_bounds__(256) void init_fused(const float* __restrict__ h,
                                                  float2* __restrict__ fusedC) {
  __shared__ float cre_l[1280], cim_l[1280], hs[1025];
  const int bid = blockIdx.x, tid = threadIdx.x;
  int w = 0;
  while (bid >= dCKB[w + 1]) ++w;
  const int local = bid - dCKB[w];
  const int jloc = local / dCPB[w];
  const int chunk = local - jloc * dCPB[w];
  const int N = cW_N[w];
  const int k = cW_K0[w] + jloc;
  const int NEp = dNEp[w], NEr = dNEr[w];
  const int v0 = chunk * 256;
  const int nlo_blk = max(0, v0 - 1024);
  const int nhi_blk = min(N - 1, v0 + 255);
  const int cnt_n = nhi_blk - nlo_blk + 1;
  const float scale = sqrtf(2.0f) / (0.5f * (float)(N - 1));
  for (int i = tid; i < 1025; i += 256) hs[i] = h[i];
  for (int i = tid; i < cnt_n; i += 256) {
    int n = nlo_blk + i;
    float win = 0.5f - 0.5f * cospif(2.0f * (float)n / (float)(N - 1));
    int r = (int)(((long long)k * (long long)n) % (long long)N);
    float ang = 2.0f * (float)r / (float)N;
    float wc = win * scale;
    cre_l[i] = wc * cospif(ang);
    cim_l[i] = wc * sinpif(ang);
  }
  __syncthreads();
  const int v = v0 + tid;
  if (v >= NEp) return;
  float2 out = make_float2(0.0f, 0.0f);
  if (v < NEr) {
    float re = 0.0f, im = 0.0f;
    for (int n = nlo_blk; n <= nhi_blk; ++n) {
      int hidx = n + 1024 - v;
      if ((unsigned)hidx <= 1024u) {
        float hv = hs[hidx];
        re = fmaf(cre_l[n - nlo_blk], hv, re);
        im = fmaf(cim_l[n - nlo_blk], hv, im);
      }
    }
    out = make_float2(re, im);
  }
  fusedC[dFB[w] + (size_t)jloc * NEp + v] = out;
}

// ---------------- init_bsplit: fusedC -> bf16 hi/lo B_T [w][col=48][k=NEp] ----------------
__global__ __launch_bounds__(256) void init_bsplit(const float2* __restrict__ fusedC,
                                                   unsigned short* __restrict__ Bhi,
                                                   unsigned short* __restrict__ Blo) {
  int gid = blockIdx.x * 256 + threadIdx.x;
  if (gid >= 491520) return;
  int w = 0;
  while (gid >= dBTb[w + 1]) ++w;
  int loc = gid - dBTb[w];
  int NEp = dNEp[w];
  int col = loc / NEp, k = loc - col * NEp;
  int nb2 = 2 * (cW_CB[w + 1] - cW_CB[w]);
  float v = 0.0f;
  if (col < nb2) {
    float2 c = fusedC[dFB[w] + (size_t)(col >> 1) * NEp + k];
    v = (col & 1) ? c.y : c.x;
  }
  unsigned int b = __float_as_uint(v);
  unsigned short hi = (unsigned short)(b >> 16);
  float r = v - __uint_as_float(b & 0xFFFF0000u);
  unsigned short lo = (unsigned short)(__float_as_uint(r) >> 16);
  Bhi[gid] = hi;
  Blo[gid] = lo;
}

// ---------------- edge_y: exact FIR output near the signal boundaries ----------------
__global__ __launch_bounds__(256) void edge_y(const float* __restrict__ x,
                                              const float* __restrict__ h,
                                              float* __restrict__ ye) {
  __shared__ float xl[1280 + 16], hs[1025];
  const int row = blockIdx.y, tid = threadIdx.x;
  const size_t rowoff = (size_t)row * T_LEN;
  const int i0 = blockIdx.x * 256;
  const int pos0 = (i0 < 1536) ? i0 : 318464 + (i0 - 1536);
  for (int i = tid; i < 1025; i += 256) hs[i] = h[i];
  for (int i = tid; i < 1280; i += 256) {
    int g = pos0 - 512 + i;
    xl[i] = ((unsigned)g < (unsigned)T_LEN) ? x[rowoff + g] : 0.0f;
  }
  __syncthreads();
  float acc = 0.0f;
  const int d = tid + 1024;
  for (int m = 0; m <= 1024; ++m) acc = fmaf(hs[m], xl[d - m], acc);
  ye[(size_t)row * 3072 + i0 + tid] = acc;
}

// ---------------- edge_dft: exact spectrum for frames where y-window exits [0,T) ----------------
__constant__ int eW[8] = {0,0,0,1,2,3,4,5};
__constant__ int eF[8] = {0,1,624,0,0,0,0,0};
__global__ __launch_bounds__(256) void edge_dft(const float* __restrict__ ye,
                                                const float2* __restrict__ coeff,
                                                float* __restrict__ Ibuf) {
  __shared__ float yl[3072];
  const int row = blockIdx.x, tid = threadIdx.x;
  for (int i = tid; i < 3072; i += 256) yl[i] = ye[(size_t)row * 3072 + i];
  __syncthreads();
  const int wv = tid >> 6, lane = tid & 63;
  for (int e = wv; e < 8; e += 4) {
    const int w = eW[e], f = eF[e];
    const int N = cW_N[w];
    const int nb = cW_CB[w + 1] - cW_CB[w];
    for (int jl = 0; jl < nb; ++jl) {
      const float2* cf = coeff + cW_CO[w] + (size_t)jl * N;
      float re = 0.0f, im = 0.0f;
      for (int n = lane; n < N; n += 64) {
        int pos = f * HOPSZ - (N >> 1) + n;
        if ((unsigned)pos < (unsigned)T_LEN) {
          int yi = (pos < 1536) ? pos : (pos - 318464 + 1536);
          float yv = yl[yi];
          float2 cs = cf[n];
          re = fmaf(yv, cs.x, re);
          im = fmaf(yv, cs.y, im);
        }
      }
#pragma unroll
      for (int off = 32; off > 0; off >>= 1) {
        re += __shfl_xor(re, off);
        im += __shfl_xor(im, off);
      }
      if (lane == 0)
        Ibuf[((size_t)row * NFRAMES + f) * NCOMP + (cW_CB[w] + jl)] = re * re + im * im;
    }
  }
}

// ---------------- MFMA fused FIR+DFT: per (row,w): [640 x NEp] @ [NEp x 48] ----------------
// 2-term bf16 split GEMM: A*B ~= Ah*Bh + Ah*Bl + Al*Bh  (error ~2^-16 relative)
__global__ __launch_bounds__(256) void sparse_mfma(const float* __restrict__ x,
                                                   const unsigned short* __restrict__ Bhi,
                                                   const unsigned short* __restrict__ Blo,
                                                   float* __restrict__ Ibuf) {
  const int mblk = blockIdx.x;       // 0..9  (64 frames each)
  const int w    = blockIdx.y;       // 0..5
  const int row  = blockIdx.z;       // 0..31
  const int NEp = dNEp[w], stb = dStb[w];
  const int nb = cW_CB[w + 1] - cW_CB[w], jb0 = cW_CB[w];
  const int tid = threadIdx.x, wave = tid >> 6, lane = tid & 63;
  const int fidx = lane & 15;        // A: frame row / B: col
  const int kg = lane >> 4;          // k-group: k = kg*8 + j
  const int fb = mblk * 64 + wave * 16;
  const int frame = fb + fidx;
  const unsigned short* BTh = Bhi + dBTb[w];
  const unsigned short* BTl = Blo + dBTb[w];
  const float* xr = x + (size_t)row * T_LEN;
  const int g0 = frame * HOPSZ + stb - 1536 + kg * 8;
  const int c0 = (0 * 16 + fidx) * NEp + kg * 8;
  const int c1 = (1 * 16 + fidx) * NEp + kg * 8;
  const int c2 = (2 * 16 + fidx) * NEp + kg * 8;
  f32x4 acc0 = {0.f,0.f,0.f,0.f}, acc1 = {0.f,0.f,0.f,0.f}, acc2 = {0.f,0.f,0.f,0.f};

  for (int kk = 0; kk < NEp; kk += 32) {
    // ---- A fragment: 8 consecutive fp32 -> bf16 hi/lo
    float xv[8];
    const int g = g0 + kk;
    if (g >= 0 && g + 8 <= T_LEN) {
      float4 p = *(const float4*)(xr + g);
      float4 q = *(const float4*)(xr + g + 4);
      xv[0] = p.x; xv[1] = p.y; xv[2] = p.z; xv[3] = p.w;
      xv[4] = q.x; xv[5] = q.y; xv[6] = q.z; xv[7] = q.w;
    } else {
#pragma unroll
      for (int j = 0; j < 8; ++j) {
        int gg = g + j;
        xv[j] = ((unsigned)gg < (unsigned)T_LEN) ? xr[gg] : 0.0f;
      }
    }
    short8v ah, al;
#pragma unroll
    for (int j = 0; j < 8; ++j) {
      unsigned int b = __float_as_uint(xv[j]);
      ah[j] = (short)(b >> 16);
      float r = xv[j] - __uint_as_float(b & 0xFFFF0000u);
      al[j] = (short)(__float_as_uint(r) >> 16);
    }
    // ---- B fragments (16B each, L2-resident)
    short8v b0h = *(const short8v*)(BTh + c0 + kk);
    short8v b1h = *(const short8v*)(BTh + c1 + kk);
    short8v b2h = *(const short8v*)(BTh + c2 + kk);
    short8v b0l = *(const short8v*)(BTl + c0 + kk);
    short8v b1l = *(const short8v*)(BTl + c1 + kk);
    short8v b2l = *(const short8v*)(BTl + c2 + kk);
    acc0 = __builtin_amdgcn_mfma_f32_16x16x32_bf16(ah, b0h, acc0, 0, 0, 0);
    acc1 = __builtin_amdgcn_mfma_f32_16x16x32_bf16(ah, b1h, acc1, 0, 0, 0);
    acc2 = __builtin_amdgcn_mfma_f32_16x16x32_bf16(ah, b2h, acc2, 0, 0, 0);
    acc0 = __builtin_amdgcn_mfma_f32_16x16x32_bf16(ah, b0l, acc0, 0, 0, 0);
    acc1 = __builtin_amdgcn_mfma_f32_16x16x32_bf16(ah, b1l, acc1, 0, 0, 0);
    acc2 = __builtin_amdgcn_mfma_f32_16x16x32_bf16(ah, b2l, acc2, 0, 0, 0);
    acc0 = __builtin_amdgcn_mfma_f32_16x16x32_bf16(al, b0h, acc0, 0, 0, 0);
    acc1 = __builtin_amdgcn_mfma_f32_16x16x32_bf16(al, b1h, acc1, 0, 0, 0);
    acc2 = __builtin_amdgcn_mfma_f32_16x16x32_bf16(al, b2h, acc2, 0, 0, 0);
  }

  // ---- epilogue: C/D layout col=lane&15, row=(lane>>4)*4+r; pair re/im via shfl_xor(1)
  const int rbase = fb + kg * 4;
#define EPI(NN, ACC)                                                          \
  {                                                                           \
    _Pragma("unroll")                                                         \
    for (int r = 0; r < 4; ++r) {                                             \
      float v = ACC[r];                                                       \
      float sq = v * v;                                                       \
      sq += __shfl_xor(sq, 1);                                                \
      int col = NN * 16 + fidx;                                               \
      int f = rbase + r;                                                      \
      if (!(col & 1)) {                                                       \
        int j = col >> 1;                                                     \
        bool edge = (f == 0) || (w == 0 && (f == 1 || f == 624));             \
        if (j < nb && f < NFRAMES && !edge)                                   \
          Ibuf[((size_t)row * NFRAMES + f) * NCOMP + jb0 + j] = sq;           \
      }                                                                       \
    }                                                                         \
  }
  EPI(0, acc0)
  EPI(1, acc1)
  EPI(2, acc2)
#undef EPI
}

// ---------------- E = I@W -> dB -> LUT interp -> n_inst[row][f][150] ----------------
__global__ __launch_bounds__(192) void espec(const float* __restrict__ Ibuf,
                                             const float* __restrict__ Wmat,
                                             const float* __restrict__ lut,
                                             float* __restrict__ ninst) {
  const int blk = blockIdx.x;           // row*625 + f
  const int c = threadIdx.x;
  const float* Irow = Ibuf + (size_t)blk * NCOMP;
  if (c < NCH) {
    float e = 0.0f;
    for (int j = 0; j < NCOMP; ++j) e = fmaf(Irow[j], Wmat[j * NCH + c], e);
    float edb = 10.0f * log10f(e * 2.5e9f + 1e-12f);   // 1/I0 = 2.5e9
    float xv = fminf(fmaxf(edb, 0.0f), 110.0f);
    float u = xv * (87.0f / 110.0f);
    int i0 = (int)u; if (i0 > 86) i0 = 86;
    float fr = u - (float)i0;
    float nv = fmaf(lut[i0 + 1] - lut[i0], fr, lut[i0]);
    ninst[(size_t)blk * NCH + c] = nv;
  }
}

// ---------------- short-term AGC over frames (8-deep pipelined loads) ----------------
__global__ void agc1(const float* __restrict__ ninst, float* __restrict__ stl) {
  int idx = blockIdx.x * 256 + threadIdx.x;
  if (idx >= NROWS * NCH) return;
  int row = idx / NCH, c = idx - row * NCH;
  const float* src = ninst + (size_t)row * NFRAMES * NCH + c;
  float* dst = stl + (size_t)row * NFRAMES * NCH + c;
  float buf[8];
#pragma unroll
  for (int i = 0; i < 8; ++i) buf[i] = src[(size_t)i * NCH];
  float s = 0.0f;
  for (int f = 0; f < NFRAMES; ++f) {
    float xv = buf[0];
#pragma unroll
    for (int i = 0; i < 7; ++i) buf[i] = buf[i + 1];
    int nf = f + 8;
    buf[7] = (nf < NFRAMES) ? src[(size_t)nf * NCH] : 0.0f;
    float a = (xv > s) ? 0.045f : 0.033f;
    s = a * xv + (1.0f - a) * s;
    dst[(size_t)f * NCH] = s;
  }
}

// ---------------- ERB smoothing + binaural inhibition + channel sum ----------------
__global__ __launch_bounds__(192) void combine(const float* __restrict__ stl,
                                               const float* __restrict__ gauss,
                                               float* __restrict__ outL,
                                               float* __restrict__ outR) {
  __shared__ float sl[NCH + 16], sr[NCH + 16], gsh[17];
  __shared__ float redL[3], redR[3];
  const int bf = blockIdx.x;
  const int b = bf / NFRAMES, f = bf - b * NFRAMES;
  const int tid = threadIdx.x;
  if (tid < NCH + 16) { sl[tid] = 0.0f; sr[tid] = 0.0f; }
  if (tid < 17) gsh[tid] = gauss[tid];
  __syncthreads();
  if (tid < NCH) {
    sl[8 + tid] = stl[((size_t)(b * 2 + 0) * NFRAMES + f) * NCH + tid];
    sr[8 + tid] = stl[((size_t)(b * 2 + 1) * NFRAMES + f) * NCH + tid];
  }
  __syncthreads();
  float vl = 0.0f, vr = 0.0f;
  if (tid < NCH) {
    float smL = 0.0f, smR = 0.0f;
#pragma unroll
    for (int t = 0; t < 17; ++t) {
      smL = fmaf(gsh[t], sl[tid + t], smL);
      smR = fmaf(gsh[t], sr[tid + t], smR);
    }
    vl = smL / coshf(1.5978f * smR);
    vr = smR / coshf(1.5978f * smL);
  }
#pragma unroll
  for (int off = 32; off > 0; off >>= 1) {
    vl += __shfl_xor(vl, off);
    vr += __shfl_xor(vr, off);
  }
  int wv = tid >> 6, lane = tid & 63;
  if (lane == 0) { redL[wv] = vl; redR[wv] = vr; }
  __syncthreads();
  if (tid == 0) {
    outL[bf] = (redL[0] + redL[1] + redL[2]) * 0.25f;
    outR[bf] = (redR[0] + redR[1] + redR[2]) * 0.25f;
  }
}

// ---------------- long-term AGC + outputs (4-deep pipelined) ----------------
__global__ void final_k(const float* __restrict__ sLst, const float* __restrict__ sRst,
                        float* __restrict__ out) {
  int b = threadIdx.x;
  if (b >= NB) return;
  float ll = 0.0f, lr = 0.0f, mx = -3.4e38f;
  float* sOut = out;
  float* lOut = out + NB * NFRAMES;
  float* mOut = out + 2 * NB * NFRAMES;
  float bufa[4], bufc[4];
#pragma unroll
  for (int i = 0; i < 4; ++i) { bufa[i] = sLst[b * NFRAMES + i]; bufc[i] = sRst[b * NFRAMES + i]; }
  for (int f = 0; f < NFRAMES; ++f) {
    float a = bufa[0], c = bufc[0];
#pragma unroll
    for (int i = 0; i < 3; ++i) { bufa[i] = bufa[i + 1]; bufc[i] = bufc[i + 1]; }
    int nf = f + 4;
    bufa[3] = (nf < NFRAMES) ? sLst[b * NFRAMES + nf] : 0.0f;
    bufc[3] = (nf < NFRAMES) ? sRst[b * NFRAMES + nf] : 0.0f;
    sOut[b * NFRAMES + f] = a + c;
    float aa = (a > ll) ? 0.01f : 0.00133f;
    ll = aa * a + (1.0f - aa) * ll;
    float ab = (c > lr) ? 0.01f : 0.00133f;
    lr = ab * c + (1.0f - ab) * lr;
    float lv = ll + lr;
    lOut[b * NFRAMES + f] = lv;
    mx = fmaxf(mx, lv);
  }
  mOut[b] = mx;
}

extern "C" void kernel_launch(void* const* d_in, const int* in_sizes, int n_in,
                              void* d_out, int out_size, void* d_ws, size_t ws_size,
                              hipStream_t stream) {
  const float* audio = (const float*)d_in[0];
  const float* ear   = (const float*)d_in[1];
  const float* lut   = (const float*)d_in[2];
  char* ws = (char*)d_ws;

  float2*         fusedC = (float2*)(ws);                   //   820,224 B
  unsigned short* BhiT   = (unsigned short*)(ws + 820480);  //   983,040 B
  unsigned short* BloT   = (unsigned short*)(ws + 1803520); //   983,040 B
  float2*         coeffO = (float2*)(ws + 2786560);         //   260,608 B
  float*          Wmat   = (float*)(ws + 3047168);          //    40,200 B
  float*          gauss  = (float*)(ws + 3087616);          //        68 B
  float*          yedge  = (float*)(ws + 3087872);          //   393,216 B
  float*          Ibuf   = (float*)(ws + 3481344);          // 5,360,000 B
  float*          ninst  = (float*)(ws + 8841472);          // 12,000,000 B
  float*          stl    = (float*)(ws + 20841728);         // 12,000,000 B
  float*          stlL   = (float*)(ws + 32841984);         //    40,000 B
  float*          stlR   = (float*)(ws + 32881984);         //    40,000 B

  hipLaunchKernelGGL(init_tables, dim3(167), dim3(256), 0, stream, coeffO, Wmat, gauss);
  hipLaunchKernelGGL(init_fused, dim3(414), dim3(256), 0, stream, ear, fusedC);
  hipLaunchKernelGGL(init_bsplit, dim3(1920), dim3(256), 0, stream, fusedC, BhiT, BloT);
  hipLaunchKernelGGL(edge_y, dim3(12, 32), dim3(256), 0, stream, audio, ear, yedge);
  hipLaunchKernelGGL(edge_dft, dim3(32), dim3(256), 0, stream, yedge, coeffO, Ibuf);
  hipLaunchKernelGGL(sparse_mfma, dim3(10, 6, 32), dim3(256), 0, stream, audio, BhiT, BloT, Ibuf);
  hipLaunchKernelGGL(espec, dim3(NROWS * NFRAMES), dim3(192), 0, stream, Ibuf, Wmat, lut, ninst);
  hipLaunchKernelGGL(agc1, dim3(19), dim3(256), 0, stream, ninst, stl);
  hipLaunchKernelGGL(combine, dim3(NB * NFRAMES), dim3(192), 0, stream, stl, gauss, stlL, stlR);
  hipLaunchKernelGGL(final_k, dim3(1), dim3(64), 0, stream, stlL, stlR, (float*)d_out);
}

// Round 5
// 557.594 us; speedup vs baseline: 1.6325x; 1.6325x over previous
//
#include <hip/hip_runtime.h>
#include <hip/hip_bf16.h>
#include <math.h>

#define T_LEN   320000
#define NB      16
#define NROWS   32          // 16 batch * 2 ch
#define NFRAMES 625
#define NCOMP   67
#define NCH     150
#define HOPSZ   512

typedef __attribute__((ext_vector_type(8))) short short8v;
typedef __attribute__((ext_vector_type(4))) float f32x4;

// per-window constants
__constant__ int cW_N[6]  = {2048,1024,512,256,128,64};
__constant__ int cW_K0[6] = {2,3,8,10,11,9};
__constant__ int cW_CB[7] = {0,4,17,29,40,46,67};
__constant__ int cW_CO[7] = {0,8192,21504,27648,30464,31232,32576};
// fused-coefficient geometry (per window)
__constant__ int dNEp[6]  = {3072,2048,1536,1280,1152,1152};
__constant__ int dNEr[6]  = {3072,2048,1536,1280,1152,1088};
__constant__ int dBTb[7]  = {0,147456,245760,319488,380928,436224,491520}; // [w][col=48][k=NEp] ushort
// init_fused chunk mapping
__constant__ int dCPB[6]  = {12,8,6,5,5,5};
__constant__ int dCKB[7]  = {0,48,152,224,279,309,414};

// ---------------- init: original DFT coeff tables, roex matrix, gauss weights ----------------
__global__ void init_tables(float2* __restrict__ coeff, float* __restrict__ Wmat,
                            float* __restrict__ gauss) {
  int gid = blockIdx.x * 256 + threadIdx.x;
  if (gid < 32576) {
    int w = 0;
    while (gid >= cW_CO[w + 1]) ++w;
    int local = gid - cW_CO[w];
    int N = cW_N[w];
    int jloc = local / N;
    int n = local - jloc * N;
    int k = cW_K0[w] + jloc;
    float win = 0.5f - 0.5f * cospif(2.0f * (float)n / (float)(N - 1));
    int r = (int)(((long long)k * (long long)n) % (long long)N);
    float ang = 2.0f * (float)r / (float)N;
    float scale = sqrtf(2.0f) / (0.5f * (float)(N - 1));
    float wc = win * scale;
    coeff[gid] = make_float2(wc * cospif(ang), wc * sinpif(ang));
  } else if (gid < 32576 + NCOMP * NCH) {
    int t = gid - 32576;
    int j = t / NCH, c = t - j * NCH;
    float erb = 1.75f + 0.25f * (float)c;
    float fc = (exp10f(erb * (1.0f / 21.366f)) - 1.0f) * (1.0f / 0.004368f);
    float erbw = 24.673f * (0.004368f * fc + 1.0f);
    float p = 4.0f * fc / erbw;
    int w = 0;
    while (j >= cW_CB[w + 1]) ++w;
    float freq = (float)(cW_K0[w] + (j - cW_CB[w])) * (32000.0f / (float)cW_N[w]);
    float g = fabsf(freq / fc - 1.0f);
    float pg = p * g;
    Wmat[j * NCH + c] = (1.0f + pg) * expf(-pg);
  } else if (gid == 32576 + NCOMP * NCH) {
    float tmp[17]; float s = 0.0f;
    for (int k = 0; k < 17; ++k) {
      float g = ((float)k - 8.0f) * 0.25f;
      tmp[k] = expf(-g * g / (2.0f * 0.08f * 0.08f));
      s += tmp[k];
    }
    for (int k = 0; k < 17; ++k) gauss[k] = tmp[k] / s;
  }
}

// ---------------- init_fused: C_j[v] = sum_n c_n h[n+1024-v], split to bf16 hi/lo B_T ----------------
__global__ __launch_bounds__(256) void init_fused(const float* __restrict__ h,
                                                  unsigned short* __restrict__ Bhi,
                                                  unsigned short* __restrict__ Blo) {
  __shared__ float cre_l[1280], cim_l[1280], hs[1025];
  const int bid = blockIdx.x, tid = threadIdx.x;
  int w = 0;
  while (bid >= dCKB[w + 1]) ++w;
  const int local = bid - dCKB[w];
  const int jloc = local / dCPB[w];
  const int chunk = local - jloc * dCPB[w];
  const int N = cW_N[w];
  const int k = cW_K0[w] + jloc;
  const int NEp = dNEp[w], NEr = dNEr[w];
  const int v0 = chunk * 256;
  const int nlo_blk = max(0, v0 - 1024);
  const int nhi_blk = min(N - 1, v0 + 255);
  const int cnt_n = nhi_blk - nlo_blk + 1;
  const float scale = sqrtf(2.0f) / (0.5f * (float)(N - 1));
  for (int i = tid; i < 1025; i += 256) hs[i] = h[i];
  for (int i = tid; i < cnt_n; i += 256) {
    int n = nlo_blk + i;
    float win = 0.5f - 0.5f * cospif(2.0f * (float)n / (float)(N - 1));
    int r = (int)(((long long)k * (long long)n) % (long long)N);
    float ang = 2.0f * (float)r / (float)N;
    float wc = win * scale;
    cre_l[i] = wc * cospif(ang);
    cim_l[i] = wc * sinpif(ang);
  }
  __syncthreads();
  const int v = v0 + tid;
  if (v >= NEp) return;
  float re = 0.0f, im = 0.0f;
  if (v < NEr) {
    for (int n = nlo_blk; n <= nhi_blk; ++n) {
      int hidx = n + 1024 - v;
      if ((unsigned)hidx <= 1024u) {
        float hv = hs[hidx];
        re = fmaf(cre_l[n - nlo_blk], hv, re);
        im = fmaf(cim_l[n - nlo_blk], hv, im);
      }
    }
  }
  size_t b0 = (size_t)dBTb[w] + (size_t)(2 * jloc) * NEp + v;
  size_t b1 = b0 + NEp;
  unsigned ur = __float_as_uint(re);
  Bhi[b0] = (unsigned short)(ur >> 16);
  Blo[b0] = (unsigned short)(__float_as_uint(re - __uint_as_float(ur & 0xFFFF0000u)) >> 16);
  unsigned ui = __float_as_uint(im);
  Bhi[b1] = (unsigned short)(ui >> 16);
  Blo[b1] = (unsigned short)(__float_as_uint(im - __uint_as_float(ui & 0xFFFF0000u)) >> 16);
}

// ---------------- edge_y: exact FIR output near the signal boundaries ----------------
__global__ __launch_bounds__(256) void edge_y(const float* __restrict__ x,
                                              const float* __restrict__ h,
                                              float* __restrict__ ye) {
  __shared__ float xl[1280 + 16], hs[1025];
  const int row = blockIdx.y, tid = threadIdx.x;
  const size_t rowoff = (size_t)row * T_LEN;
  const int i0 = blockIdx.x * 256;
  const int pos0 = (i0 < 1536) ? i0 : 318464 + (i0 - 1536);
  for (int i = tid; i < 1025; i += 256) hs[i] = h[i];
  for (int i = tid; i < 1280; i += 256) {
    int g = pos0 - 512 + i;
    xl[i] = ((unsigned)g < (unsigned)T_LEN) ? x[rowoff + g] : 0.0f;
  }
  __syncthreads();
  float acc = 0.0f;
  const int d = tid + 1024;
  for (int m = 0; m <= 1024; ++m) acc = fmaf(hs[m], xl[d - m], acc);
  ye[(size_t)row * 3072 + i0 + tid] = acc;
}

// ---------------- edge_dft: exact spectrum for frames whose y-window exits [0,T) ----------------
__constant__ int eW[8] = {0,0,0,1,2,3,4,5};
__constant__ int eF[8] = {0,1,624,0,0,0,0,0};
__global__ __launch_bounds__(256) void edge_dft(const float* __restrict__ ye,
                                                const float2* __restrict__ coeff,
                                                float* __restrict__ Ibuf) {
  __shared__ float yl[3072];
  const int row = blockIdx.x, tid = threadIdx.x;
  for (int i = tid; i < 3072; i += 256) yl[i] = ye[(size_t)row * 3072 + i];
  __syncthreads();
  const int wv = tid >> 6, lane = tid & 63;
  for (int e = wv; e < 8; e += 4) {
    const int w = eW[e], f = eF[e];
    const int N = cW_N[w];
    const int nb = cW_CB[w + 1] - cW_CB[w];
    for (int jl = 0; jl < nb; ++jl) {
      const float2* cf = coeff + cW_CO[w] + (size_t)jl * N;
      float re = 0.0f, im = 0.0f;
      for (int n = lane; n < N; n += 64) {
        int pos = f * HOPSZ - (N >> 1) + n;
        if ((unsigned)pos < (unsigned)T_LEN) {
          int yi = (pos < 1536) ? pos : (pos - 318464 + 1536);
          float yv = yl[yi];
          float2 cs = cf[n];
          re = fmaf(yv, cs.x, re);
          im = fmaf(yv, cs.y, im);
        }
      }
#pragma unroll
      for (int off = 32; off > 0; off >>= 1) {
        re += __shfl_xor(re, off);
        im += __shfl_xor(im, off);
      }
      if (lane == 0)
        Ibuf[((size_t)row * NFRAMES + f) * NCOMP + (cW_CB[w] + jl)] = re * re + im * im;
    }
  }
}

// ---------------- MFMA fused FIR+DFT with LDS-staged bf16 A ----------------
#define TILE_X 18944   // 31*512 + 3072
#define SWZ(i) ((i) ^ ((((i) >> 9) & 7) << 3))

template<int W, int CT0, int NCT>
__device__ __forceinline__ void gemm_task(const unsigned short* sxh, const unsigned short* sxl,
                                          const unsigned short* __restrict__ Bhi,
                                          const unsigned short* __restrict__ Blo,
                                          float* __restrict__ Ibuf, int row, int f0, int lane) {
  constexpr int kNEp[6] = {3072,2048,1536,1280,1152,1152};
  constexpr int kStb[6] = {0,512,768,896,960,992};    // 1536 - (N+1024)/2
  constexpr int kNb[6]  = {4,13,12,11,6,21};
  constexpr int kJb0[6] = {0,4,17,29,40,46};
  constexpr int kBtb[6] = {0,147456,245760,319488,380928,436224};
  constexpr int NEp = kNEp[W], stb = kStb[W], nb = kNb[W], jb0 = kJb0[W];
  const int fidx = lane & 15, kg = lane >> 4;
  const unsigned short* Bh = Bhi + kBtb[W] + (size_t)((CT0 * 16 + fidx) * NEp + kg * 8);
  const unsigned short* Bl = Blo + kBtb[W] + (size_t)((CT0 * 16 + fidx) * NEp + kg * 8);
  const int ib0 = fidx * 512 + stb + kg * 8;
  const int ib1 = ib0 + 16 * 512;
  f32x4 acc[NCT][2];
#pragma unroll
  for (int ct = 0; ct < NCT; ++ct) {
    acc[ct][0] = (f32x4){0.f,0.f,0.f,0.f};
    acc[ct][1] = (f32x4){0.f,0.f,0.f,0.f};
  }
#pragma unroll 2
  for (int kk = 0; kk < NEp; kk += 32) {
    const int i0 = SWZ(ib0 + kk);
    const int i1 = SWZ(ib1 + kk);
    short8v ah0 = *(const short8v*)(sxh + i0);
    short8v al0 = *(const short8v*)(sxl + i0);
    short8v ah1 = *(const short8v*)(sxh + i1);
    short8v al1 = *(const short8v*)(sxl + i1);
#pragma unroll
    for (int ct = 0; ct < NCT; ++ct) {
      short8v bh = *(const short8v*)(Bh + ct * 16 * NEp + kk);
      short8v bl = *(const short8v*)(Bl + ct * 16 * NEp + kk);
      acc[ct][0] = __builtin_amdgcn_mfma_f32_16x16x32_bf16(ah0, bh, acc[ct][0], 0, 0, 0);
      acc[ct][1] = __builtin_amdgcn_mfma_f32_16x16x32_bf16(ah1, bh, acc[ct][1], 0, 0, 0);
      acc[ct][0] = __builtin_amdgcn_mfma_f32_16x16x32_bf16(ah0, bl, acc[ct][0], 0, 0, 0);
      acc[ct][1] = __builtin_amdgcn_mfma_f32_16x16x32_bf16(ah1, bl, acc[ct][1], 0, 0, 0);
      acc[ct][0] = __builtin_amdgcn_mfma_f32_16x16x32_bf16(al0, bh, acc[ct][0], 0, 0, 0);
      acc[ct][1] = __builtin_amdgcn_mfma_f32_16x16x32_bf16(al1, bh, acc[ct][1], 0, 0, 0);
    }
  }
#pragma unroll
  for (int ct = 0; ct < NCT; ++ct)
#pragma unroll
    for (int m = 0; m < 2; ++m)
#pragma unroll
      for (int r = 0; r < 4; ++r) {
        float v = acc[ct][m][r];
        float sq = v * v;
        sq += __shfl_xor(sq, 1);
        int col = (CT0 + ct) * 16 + fidx;
        int f = f0 + m * 16 + kg * 4 + r;
        if (!(col & 1)) {
          int j = col >> 1;
          bool edge = (f == 0) || (W == 0 && (f == 1 || f == 624));
          if (j < nb && f < NFRAMES && !edge)
            Ibuf[((size_t)row * NFRAMES + f) * NCOMP + jb0 + j] = sq;
        }
      }
}

__global__ __launch_bounds__(256) void sparse_mfma(const float* __restrict__ x,
                                                   const unsigned short* __restrict__ Bhi,
                                                   const unsigned short* __restrict__ Blo,
                                                   float* __restrict__ Ibuf) {
  __shared__ __align__(16) unsigned short sxh[TILE_X];
  __shared__ __align__(16) unsigned short sxl[TILE_X];
  const int fblk = blockIdx.x, row = blockIdx.y;
  const int f0 = fblk * 32;
  const int tid = threadIdx.x;
  const float* xr = x + (size_t)row * T_LEN;
  const int lo = f0 * HOPSZ - 1536;
  for (int i = 4 * tid; i < TILE_X; i += 1024) {
    const int g = lo + i;
    float v[4];
    if (g >= 0 && g + 4 <= T_LEN) {
      float4 p = *(const float4*)(xr + g);
      v[0] = p.x; v[1] = p.y; v[2] = p.z; v[3] = p.w;
    } else {
#pragma unroll
      for (int q = 0; q < 4; ++q) {
        int gg = g + q;
        v[q] = ((unsigned)gg < (unsigned)T_LEN) ? xr[gg] : 0.0f;
      }
    }
    unsigned short h4[4], l4[4];
#pragma unroll
    for (int q = 0; q < 4; ++q) {
      unsigned u = __float_as_uint(v[q]);
      h4[q] = (unsigned short)(u >> 16);
      float r = v[q] - __uint_as_float(u & 0xFFFF0000u);
      l4[q] = (unsigned short)(__float_as_uint(r) >> 16);
    }
    const int is = SWZ(i);
    *(ushort4*)(sxh + is) = make_ushort4(h4[0], h4[1], h4[2], h4[3]);
    *(ushort4*)(sxl + is) = make_ushort4(l4[0], l4[1], l4[2], l4[3]);
  }
  __syncthreads();
  const int wave = tid >> 6, lane = tid & 63;
  if (wave == 0) {
    gemm_task<0,0,1>(sxh, sxl, Bhi, Blo, Ibuf, row, f0, lane);
    gemm_task<4,0,1>(sxh, sxl, Bhi, Blo, Ibuf, row, f0, lane);
  } else if (wave == 1) {
    gemm_task<1,0,2>(sxh, sxl, Bhi, Blo, Ibuf, row, f0, lane);
  } else if (wave == 2) {
    gemm_task<2,0,2>(sxh, sxl, Bhi, Blo, Ibuf, row, f0, lane);
    gemm_task<3,0,1>(sxh, sxl, Bhi, Blo, Ibuf, row, f0, lane);
  } else {
    gemm_task<3,1,1>(sxh, sxl, Bhi, Blo, Ibuf, row, f0, lane);
    gemm_task<5,0,3>(sxh, sxl, Bhi, Blo, Ibuf, row, f0, lane);
  }
}

// ---------------- E = I@W -> dB -> LUT interp -> n_inst[row][f][150] ----------------
__global__ __launch_bounds__(192) void espec(const float* __restrict__ Ibuf,
                                             const float* __restrict__ Wmat,
                                             const float* __restrict__ lut,
                                             float* __restrict__ ninst) {
  const int blk = blockIdx.x;           // row*625 + f
  const int c = threadIdx.x;
  const float* Irow = Ibuf + (size_t)blk * NCOMP;
  if (c < NCH) {
    float e = 0.0f;
    for (int j = 0; j < NCOMP; ++j) e = fmaf(Irow[j], Wmat[j * NCH + c], e);
    float edb = 10.0f * log10f(e * 2.5e9f + 1e-12f);   // 1/I0 = 2.5e9
    float xv = fminf(fmaxf(edb, 0.0f), 110.0f);
    float u = xv * (87.0f / 110.0f);
    int i0 = (int)u; if (i0 > 86) i0 = 86;
    float fr = u - (float)i0;
    float nv = fmaf(lut[i0 + 1] - lut[i0], fr, lut[i0]);
    ninst[(size_t)blk * NCH + c] = nv;
  }
}

// ---------------- short-term AGC over frames (8-deep pipelined loads) ----------------
__global__ void agc1(const float* __restrict__ ninst, float* __restrict__ stl) {
  int idx = blockIdx.x * 64 + threadIdx.x;
  if (idx >= NROWS * NCH) return;
  int row = idx / NCH, c = idx - row * NCH;
  const float* src = ninst + (size_t)row * NFRAMES * NCH + c;
  float* dst = stl + (size_t)row * NFRAMES * NCH + c;
  float buf[8];
#pragma unroll
  for (int i = 0; i < 8; ++i) buf[i] = src[(size_t)i * NCH];
  float s = 0.0f;
  for (int f = 0; f < NFRAMES; ++f) {
    float xv = buf[0];
#pragma unroll
    for (int i = 0; i < 7; ++i) buf[i] = buf[i + 1];
    int nf = f + 8;
    buf[7] = (nf < NFRAMES) ? src[(size_t)nf * NCH] : 0.0f;
    float a = (xv > s) ? 0.045f : 0.033f;
    s = a * xv + (1.0f - a) * s;
    dst[(size_t)f * NCH] = s;
  }
}

// ---------------- ERB smoothing + binaural inhibition + channel sum ----------------
__global__ __launch_bounds__(192) void combine(const float* __restrict__ stl,
                                               const float* __restrict__ gauss,
                                               float* __restrict__ outL,
                                               float* __restrict__ outR) {
  __shared__ float sl[NCH + 16], sr[NCH + 16], gsh[17];
  __shared__ float redL[3], redR[3];
  const int bf = blockIdx.x;
  const int b = bf / NFRAMES, f = bf - b * NFRAMES;
  const int tid = threadIdx.x;
  if (tid < NCH + 16) { sl[tid] = 0.0f; sr[tid] = 0.0f; }
  if (tid < 17) gsh[tid] = gauss[tid];
  __syncthreads();
  if (tid < NCH) {
    sl[8 + tid] = stl[((size_t)(b * 2 + 0) * NFRAMES + f) * NCH + tid];
    sr[8 + tid] = stl[((size_t)(b * 2 + 1) * NFRAMES + f) * NCH + tid];
  }
  __syncthreads();
  float vl = 0.0f, vr = 0.0f;
  if (tid < NCH) {
    float smL = 0.0f, smR = 0.0f;
#pragma unroll
    for (int t = 0; t < 17; ++t) {
      smL = fmaf(gsh[t], sl[tid + t], smL);
      smR = fmaf(gsh[t], sr[tid + t], smR);
    }
    vl = smL / coshf(1.5978f * smR);
    vr = smR / coshf(1.5978f * smL);
  }
#pragma unroll
  for (int off = 32; off > 0; off >>= 1) {
    vl += __shfl_xor(vl, off);
    vr += __shfl_xor(vr, off);
  }
  int wv = tid >> 6, lane = tid & 63;
  if (lane == 0) { redL[wv] = vl; redR[wv] = vr; }
  __syncthreads();
  if (tid == 0) {
    outL[bf] = (redL[0] + redL[1] + redL[2]) * 0.25f;
    outR[bf] = (redR[0] + redR[1] + redR[2]) * 0.25f;
  }
}

// ---------------- long-term AGC + outputs (8-deep pipelined) ----------------
__global__ void final_k(const float* __restrict__ sLst, const float* __restrict__ sRst,
                        float* __restrict__ out) {
  int b = threadIdx.x;
  if (b >= NB) return;
  float ll = 0.0f, lr = 0.0f, mx = -3.4e38f;
  float* sOut = out;
  float* lOut = out + NB * NFRAMES;
  float* mOut = out + 2 * NB * NFRAMES;
  float bufa[8], bufc[8];
#pragma unroll
  for (int i = 0; i < 8; ++i) { bufa[i] = sLst[b * NFRAMES + i]; bufc[i] = sRst[b * NFRAMES + i]; }
  for (int f = 0; f < NFRAMES; ++f) {
    float a = bufa[0], c = bufc[0];
#pragma unroll
    for (int i = 0; i < 7; ++i) { bufa[i] = bufa[i + 1]; bufc[i] = bufc[i + 1]; }
    int nf = f + 8;
    bufa[7] = (nf < NFRAMES) ? sLst[b * NFRAMES + nf] : 0.0f;
    bufc[7] = (nf < NFRAMES) ? sRst[b * NFRAMES + nf] : 0.0f;
    sOut[b * NFRAMES + f] = a + c;
    float aa = (a > ll) ? 0.01f : 0.00133f;
    ll = aa * a + (1.0f - aa) * ll;
    float ab = (c > lr) ? 0.01f : 0.00133f;
    lr = ab * c + (1.0f - ab) * lr;
    float lv = ll + lr;
    lOut[b * NFRAMES + f] = lv;
    mx = fmaxf(mx, lv);
  }
  mOut[b] = mx;
}

extern "C" void kernel_launch(void* const* d_in, const int* in_sizes, int n_in,
                              void* d_out, int out_size, void* d_ws, size_t ws_size,
                              hipStream_t stream) {
  const float* audio = (const float*)d_in[0];
  const float* ear   = (const float*)d_in[1];
  const float* lut   = (const float*)d_in[2];
  char* ws = (char*)d_ws;

  unsigned short* BhiT   = (unsigned short*)(ws);            //   983,040 B
  unsigned short* BloT   = (unsigned short*)(ws + 983040);   //   983,040 B
  float2*         coeffO = (float2*)(ws + 1966080);          //   260,608 B
  float*          Wmat   = (float*)(ws + 2226688);           //    40,200 B
  float*          gauss  = (float*)(ws + 2266888);           //        68 B
  float*          yedge  = (float*)(ws + 2266960);           //   393,216 B
  float*          Ibuf   = (float*)(ws + 2660176);           // 5,360,000 B
  float*          ninst  = (float*)(ws + 8020176);           // 12,000,000 B
  float*          stl    = (float*)(ws + 20020176);          // 12,000,000 B
  float*          stlL   = (float*)(ws + 32020176);          //    40,000 B
  float*          stlR   = (float*)(ws + 32060176);          //    40,000 B

  hipLaunchKernelGGL(init_tables, dim3(167), dim3(256), 0, stream, coeffO, Wmat, gauss);
  hipLaunchKernelGGL(init_fused, dim3(414), dim3(256), 0, stream, ear, BhiT, BloT);
  hipLaunchKernelGGL(edge_y, dim3(12, 32), dim3(256), 0, stream, audio, ear, yedge);
  hipLaunchKernelGGL(edge_dft, dim3(32), dim3(256), 0, stream, yedge, coeffO, Ibuf);
  hipLaunchKernelGGL(sparse_mfma, dim3(20, 32), dim3(256), 0, stream, audio, BhiT, BloT, Ibuf);
  hipLaunchKernelGGL(espec, dim3(NROWS * NFRAMES), dim3(192), 0, stream, Ibuf, Wmat, lut, ninst);
  hipLaunchKernelGGL(agc1, dim3(75), dim3(64), 0, stream, ninst, stl);
  hipLaunchKernelGGL(combine, dim3(NB * NFRAMES), dim3(192), 0, stream, stl, gauss, stlL, stlR);
  hipLaunchKernelGGL(final_k, dim3(1), dim3(64), 0, stream, stlL, stlR, (float*)d_out);
}